// Round 1
// baseline (635.980 us; speedup 1.0000x reference)
//
#include <hip/hip_runtime.h>
#include <math.h>

#define B_ 16
#define P_ 19248
#define C_ 81
#define O_ 32
#define POS_TH 0.5f
#define NEG_TH 0.4f

__device__ __forceinline__ float sl1(float x) {
    float d = fabsf(x);
    return (d < 1.0f) ? 0.5f * d * d : d - 0.5f;
}

// IoU between gt (point form x1,y1,x2,y2) and prior (center form cx,cy,w,h),
// replicating the reference's exact arithmetic (point-form conversion first).
__device__ __forceinline__ float iou_gt_prior(float4 t, float4 pr) {
    float px1 = pr.x - pr.z * 0.5f;
    float py1 = pr.y - pr.w * 0.5f;
    float px2 = pr.x + pr.z * 0.5f;
    float py2 = pr.y + pr.w * 0.5f;
    float ltx = fmaxf(t.x, px1), lty = fmaxf(t.y, py1);
    float rbx = fminf(t.z, px2), rby = fminf(t.w, py2);
    float iw = fmaxf(rbx - ltx, 0.0f), ih = fmaxf(rby - lty, 0.0f);
    float inter = iw * ih;
    float area_t = (t.z - t.x) * (t.w - t.y);
    float area_p = (px2 - px1) * (py2 - py1);
    return inter / (area_t + area_p - inter);
}

__global__ void k_init(int* num_pos, float* accum) {
    int t = threadIdx.x;
    if (t < B_) num_pos[t] = 0;
    if (t < 2) accum[t] = 0.0f;
}

// One block per (b,o): argmax over P priors (first occurrence on ties).
__global__ void k_best_prior(const float* __restrict__ priors,
                             const float* __restrict__ gt_boxes,
                             int* __restrict__ best_pr) {
    int b = blockIdx.x / O_;
    int o = blockIdx.x % O_;
    float4 t = ((const float4*)gt_boxes)[b * O_ + o];
    float bestv = -1.0f; int besti = 0;
    for (int p = threadIdx.x; p < P_; p += blockDim.x) {
        float4 pr = ((const float4*)priors)[p];
        float v = iou_gt_prior(t, pr);
        if (v > bestv) { bestv = v; besti = p; }
    }
    __shared__ float sv[256];
    __shared__ int   si[256];
    sv[threadIdx.x] = bestv; si[threadIdx.x] = besti;
    __syncthreads();
    for (int s = 128; s > 0; s >>= 1) {
        if (threadIdx.x < s) {
            float ov = sv[threadIdx.x + s]; int oi = si[threadIdx.x + s];
            if (ov > sv[threadIdx.x] ||
                (ov == sv[threadIdx.x] && oi < si[threadIdx.x])) {
                sv[threadIdx.x] = ov; si[threadIdx.x] = oi;
            }
        }
        __syncthreads();
    }
    if (threadIdx.x == 0) best_pr[b * O_ + o] = si[0];
}

// One thread per (b,p): max/argmax over O gts (first occurrence on ties).
__global__ void k_best_truth(const float* __restrict__ priors,
                             const float* __restrict__ gt_boxes,
                             float* __restrict__ bt_ov,
                             int* __restrict__ bt_ix) {
    int b = blockIdx.y;
    int p = blockIdx.x * blockDim.x + threadIdx.x;
    __shared__ float4 gt[O_];
    if (threadIdx.x < O_) gt[threadIdx.x] = ((const float4*)gt_boxes)[b * O_ + threadIdx.x];
    __syncthreads();
    if (p >= P_) return;
    float4 pr = ((const float4*)priors)[p];
    float bestv = -1.0f; int besti = 0;
    for (int o = 0; o < O_; ++o) {
        float v = iou_gt_prior(gt[o], pr);
        if (v > bestv) { bestv = v; besti = o; }
    }
    size_t bp = (size_t)b * P_ + p;
    bt_ov[bp] = bestv;
    bt_ix[bp] = besti;
}

// Force-match: sequential per batch so duplicate best-priors resolve last-wins
// (numpy scatter semantics).
__global__ void k_force(const int* __restrict__ best_pr,
                        float* __restrict__ bt_ov,
                        int* __restrict__ bt_ix) {
    int b = threadIdx.x;
    if (b >= B_) return;
    for (int o = 0; o < O_; ++o) {
        int p = best_pr[b * O_ + o];
        size_t bp = (size_t)b * P_ + p;
        bt_ov[bp] = 2.0f;
        bt_ix[bp] = o;
    }
}

// Wave-per-prior main pass: logsumexp over C=81, conf_t, smooth-L1 on pos,
// per-prior loss_c / ce_neg to workspace, block-then-global accumulation.
__global__ void k_main(const float* __restrict__ loc_data,
                       const float* __restrict__ conf_data,
                       const float* __restrict__ priors,
                       const float* __restrict__ gt_boxes,
                       const int* __restrict__ gt_labels,
                       const float* __restrict__ bt_ov,
                       const int* __restrict__ bt_ix,
                       float* __restrict__ lossc,
                       float* __restrict__ ce_neg,
                       int* __restrict__ num_pos,
                       float* __restrict__ accum) {
    int wave = threadIdx.x >> 6;
    int lane = threadIdx.x & 63;
    size_t bp = (size_t)blockIdx.x * 4 + wave;   // B_*P_ divisible by 4
    int b = (int)(bp / P_);
    int p = (int)(bp % P_);

    const float* crow = conf_data + bp * C_;
    float c0 = crow[lane];
    float c1 = (lane < C_ - 64) ? crow[64 + lane] : -INFINITY;

    float m = fmaxf(c0, c1);
    #pragma unroll
    for (int s = 32; s > 0; s >>= 1) m = fmaxf(m, __shfl_xor(m, s));
    float e = expf(c0 - m) + ((lane < C_ - 64) ? expf(c1 - m) : 0.0f);
    #pragma unroll
    for (int s = 32; s > 0; s >>= 1) e += __shfl_xor(e, s);
    float logZ = m + logf(e);

    // wave-uniform scalar work (computed redundantly on all lanes)
    float ov = bt_ov[bp];
    int ti = bt_ix[bp];
    int conf_t = gt_labels[b * O_ + ti] + 1;
    if (ov < POS_TH) conf_t = -1;
    if (ov < NEG_TH) conf_t = 0;
    bool pos = conf_t > 0;

    float conf0 = __shfl(c0, 0);
    float lc = (pos || conf_t < 0) ? 0.0f : (logZ - conf0);
    int cls = pos ? conf_t : 0;
    float ccls = (cls < 64) ? __shfl(c0, cls) : __shfl(c1, cls - 64);
    float ce = logZ - ccls;

    __shared__ float s_lB, s_ceP;
    __shared__ int s_np;
    if (threadIdx.x == 0) { s_lB = 0.0f; s_ceP = 0.0f; s_np = 0; }
    __syncthreads();

    if (lane == 0) {
        lossc[bp] = lc;
        ce_neg[bp] = (conf_t == 0) ? ce : 0.0f;
        if (pos) {
            float4 t = ((const float4*)gt_boxes)[b * O_ + ti];   // matched gt (point form)
            float4 pr = ((const float4*)priors)[p];              // prior (center form)
            float mcx = (t.x + t.z) * 0.5f;
            float mcy = (t.y + t.w) * 0.5f;
            float gx = (mcx - pr.x) / (0.1f * pr.z);
            float gy = (mcy - pr.y) / (0.1f * pr.w);
            float gw = logf((t.z - t.x) / pr.z) / 0.2f;
            float gh = logf((t.w - t.y) / pr.w) / 0.2f;
            float4 ld = ((const float4*)loc_data)[bp];
            float s = sl1(ld.x - gx) + sl1(ld.y - gy) + sl1(ld.z - gw) + sl1(ld.w - gh);
            atomicAdd(&s_lB, s);
            atomicAdd(&s_ceP, ce);
            atomicAdd(&s_np, 1);
        }
    }
    __syncthreads();
    if (threadIdx.x == 0 && s_np > 0) {
        atomicAdd(&accum[0], s_lB);
        atomicAdd(&accum[1], s_ceP);
        atomicAdd(&num_pos[b], s_np);
    }
}

// One block per batch: exact top-k select via 64-bit radix select.
// key = float_bits(loss_c) << 32 | ~index  reproduces stable argsort(-loss_c)
// tie-breaking exactly (value desc, index asc); keys are unique.
__global__ void k_select(const float* __restrict__ lossc,
                         const float* __restrict__ ce_neg,
                         const int* __restrict__ num_pos,
                         float* __restrict__ ce_sum) {
    int b = blockIdx.x;
    const float* lc = lossc + (size_t)b * P_;
    const float* cn = ce_neg + (size_t)b * P_;
    int k = 3 * num_pos[b];
    if (k > P_ - 1) k = P_ - 1;

    __shared__ int hist[256];
    __shared__ unsigned long long s_prefix;
    __shared__ int s_k;
    if (threadIdx.x == 0) { s_prefix = 0ULL; s_k = k; }
    __syncthreads();

    if (k <= 0) {                       // k is block-uniform
        if (threadIdx.x == 0) ce_sum[b] = 0.0f;
        return;
    }

    for (int d = 7; d >= 0; --d) {
        for (int i = threadIdx.x; i < 256; i += blockDim.x) hist[i] = 0;
        __syncthreads();
        unsigned long long pref = s_prefix;
        unsigned long long pmask = (d == 7) ? 0ULL : ((~0ULL) << ((d + 1) * 8));
        for (int i = threadIdx.x; i < P_; i += blockDim.x) {
            unsigned int fb = __float_as_uint(lc[i]);
            unsigned long long key =
                ((unsigned long long)fb << 32) | (unsigned int)(0xFFFFFFFFu - (unsigned int)i);
            if ((key & pmask) == pref)
                atomicAdd(&hist[(int)((key >> (d * 8)) & 255)], 1);
        }
        __syncthreads();
        if (threadIdx.x == 0) {
            int kk = s_k, cum = 0, bin = 255;
            for (; bin >= 1; --bin) {
                if (cum + hist[bin] >= kk) break;
                cum += hist[bin];
            }
            s_prefix = pref | ((unsigned long long)bin << (d * 8));
            s_k = kk - cum;
        }
        __syncthreads();
    }

    unsigned long long T = s_prefix;    // k-th largest key; select key >= T
    float sum = 0.0f;
    for (int i = threadIdx.x; i < P_; i += blockDim.x) {
        unsigned int fb = __float_as_uint(lc[i]);
        unsigned long long key =
            ((unsigned long long)fb << 32) | (unsigned int)(0xFFFFFFFFu - (unsigned int)i);
        if (key >= T) sum += cn[i];     // cn is 0 for non-valid-negatives
    }
    __shared__ float red[1024];
    red[threadIdx.x] = sum;
    __syncthreads();
    for (int s = (int)blockDim.x / 2; s > 0; s >>= 1) {
        if (threadIdx.x < s) red[threadIdx.x] += red[threadIdx.x + s];
        __syncthreads();
    }
    if (threadIdx.x == 0) ce_sum[b] = red[0];
}

__global__ void k_final(const int* __restrict__ num_pos,
                        const float* __restrict__ ce_sum,
                        const float* __restrict__ accum,
                        float* __restrict__ out) {
    if (threadIdx.x != 0) return;
    int tp = 0; float ns = 0.0f;
    for (int b = 0; b < B_; ++b) { tp += num_pos[b]; ns += ce_sum[b]; }
    float inv = 1.0f / (float)tp;
    out[0] = accum[0] * 1.5f * inv;          // BBOX_ALPHA
    out[1] = (accum[1] + ns) * 1.0f * inv;   // CONF_ALPHA
}

extern "C" void kernel_launch(void* const* d_in, const int* in_sizes, int n_in,
                              void* d_out, int out_size, void* d_ws, size_t ws_size,
                              hipStream_t stream) {
    const float* loc    = (const float*)d_in[0];
    const float* conf   = (const float*)d_in[1];
    const float* priors = (const float*)d_in[2];
    const float* gtb    = (const float*)d_in[3];
    const int*   gtl    = (const int*)d_in[4];
    float* out = (float*)d_out;

    const size_t BP = (size_t)B_ * P_;
    float* bt_ov   = (float*)d_ws;
    int*   bt_ix   = (int*)d_ws + BP;
    float* lossc   = (float*)d_ws + 2 * BP;
    float* ce_neg  = (float*)d_ws + 3 * BP;
    int*   best_pr = (int*)d_ws + 4 * BP;
    int*   num_pos = (int*)d_ws + 4 * BP + B_ * O_;
    float* ce_sum  = (float*)d_ws + 4 * BP + B_ * O_ + B_;
    float* accum   = (float*)d_ws + 4 * BP + B_ * O_ + 2 * B_;

    hipLaunchKernelGGL(k_init, dim3(1), dim3(64), 0, stream, num_pos, accum);
    hipLaunchKernelGGL(k_best_prior, dim3(B_ * O_), dim3(256), 0, stream,
                       priors, gtb, best_pr);
    hipLaunchKernelGGL(k_best_truth, dim3((P_ + 255) / 256, B_), dim3(256), 0, stream,
                       priors, gtb, bt_ov, bt_ix);
    hipLaunchKernelGGL(k_force, dim3(1), dim3(64), 0, stream, best_pr, bt_ov, bt_ix);
    hipLaunchKernelGGL(k_main, dim3((int)(BP / 4)), dim3(256), 0, stream,
                       loc, conf, priors, gtb, gtl, bt_ov, bt_ix,
                       lossc, ce_neg, num_pos, accum);
    hipLaunchKernelGGL(k_select, dim3(B_), dim3(1024), 0, stream,
                       lossc, ce_neg, num_pos, ce_sum);
    hipLaunchKernelGGL(k_final, dim3(1), dim3(64), 0, stream,
                       num_pos, ce_sum, accum, out);
}

// Round 2
// 234.665 us; speedup vs baseline: 2.7102x; 2.7102x over previous
//
#include <hip/hip_runtime.h>
#include <math.h>

#define B_ 16
#define P_ 19248
#define C_ 81
#define O_ 32
#define POS_TH 0.5f
#define NEG_TH 0.4f
#define RPB 128            // rows per block in k_main; B_*P_ = 307968 = 2406*128

__device__ __forceinline__ float sl1(float x) {
    float d = fabsf(x);
    return (d < 1.0f) ? 0.5f * d * d : d - 0.5f;
}

__device__ __forceinline__ float iou_gt_prior(float4 t, float4 pr) {
    float px1 = pr.x - pr.z * 0.5f;
    float py1 = pr.y - pr.w * 0.5f;
    float px2 = pr.x + pr.z * 0.5f;
    float py2 = pr.y + pr.w * 0.5f;
    float ltx = fmaxf(t.x, px1), lty = fmaxf(t.y, py1);
    float rbx = fminf(t.z, px2), rby = fminf(t.w, py2);
    float iw = fmaxf(rbx - ltx, 0.0f), ih = fmaxf(rby - lty, 0.0f);
    float inter = iw * ih;
    float area_t = (t.z - t.x) * (t.w - t.y);
    float area_p = (px2 - px1) * (py2 - py1);
    return inter / (area_t + area_p - inter);
}

__global__ void k_init(int* num_pos, float* accum) {
    int t = threadIdx.x;
    if (t < B_) num_pos[t] = 0;
    if (t < 2) accum[t] = 0.0f;
}

// One block per (b,o): argmax over P priors (first occurrence on ties).
__global__ void k_best_prior(const float* __restrict__ priors,
                             const float* __restrict__ gt_boxes,
                             int* __restrict__ best_pr) {
    int b = blockIdx.x / O_;
    int o = blockIdx.x % O_;
    float4 t = ((const float4*)gt_boxes)[b * O_ + o];
    float bestv = -1.0f; int besti = 0;
    for (int p = threadIdx.x; p < P_; p += blockDim.x) {
        float4 pr = ((const float4*)priors)[p];
        float v = iou_gt_prior(t, pr);
        if (v > bestv) { bestv = v; besti = p; }
    }
    __shared__ float sv[256];
    __shared__ int   si[256];
    sv[threadIdx.x] = bestv; si[threadIdx.x] = besti;
    __syncthreads();
    for (int s = 128; s > 0; s >>= 1) {
        if (threadIdx.x < s) {
            float ov = sv[threadIdx.x + s]; int oi = si[threadIdx.x + s];
            if (ov > sv[threadIdx.x] ||
                (ov == sv[threadIdx.x] && oi < si[threadIdx.x])) {
                sv[threadIdx.x] = ov; si[threadIdx.x] = oi;
            }
        }
        __syncthreads();
    }
    if (threadIdx.x == 0) best_pr[b * O_ + o] = si[0];
}

// One thread per (b,p): max/argmax over O gts (first occurrence on ties).
__global__ void k_best_truth(const float* __restrict__ priors,
                             const float* __restrict__ gt_boxes,
                             float* __restrict__ bt_ov,
                             int* __restrict__ bt_ix) {
    int b = blockIdx.y;
    int p = blockIdx.x * blockDim.x + threadIdx.x;
    __shared__ float4 gt[O_];
    if (threadIdx.x < O_) gt[threadIdx.x] = ((const float4*)gt_boxes)[b * O_ + threadIdx.x];
    __syncthreads();
    if (p >= P_) return;
    float4 pr = ((const float4*)priors)[p];
    float bestv = -1.0f; int besti = 0;
    for (int o = 0; o < O_; ++o) {
        float v = iou_gt_prior(gt[o], pr);
        if (v > bestv) { bestv = v; besti = o; }
    }
    size_t bp = (size_t)b * P_ + p;
    bt_ov[bp] = bestv;
    bt_ix[bp] = besti;
}

// Force-match: sequential per batch (numpy last-wins scatter semantics).
__global__ void k_force(const int* __restrict__ best_pr,
                        float* __restrict__ bt_ov,
                        int* __restrict__ bt_ix) {
    int b = threadIdx.x;
    if (b >= B_) return;
    for (int o = 0; o < O_; ++o) {
        int p = best_pr[b * O_ + o];
        size_t bp = (size_t)b * P_ + p;
        bt_ov[bp] = 2.0f;
        bt_ix[bp] = o;
    }
}

// Thread-per-row main pass with LDS row staging.
// 128 threads own 128 consecutive rows; stage 41472B via coalesced float4
// (all loads issued before any LDS write -> deep pipeline), then each thread
// reduces its own row from LDS (stride 81 dwords = 2-way banks = free).
__global__ __launch_bounds__(RPB) void
k_main(const float* __restrict__ loc_data,
       const float* __restrict__ conf_data,
       const float* __restrict__ priors,
       const float* __restrict__ gt_boxes,
       const int* __restrict__ gt_labels,
       const float* __restrict__ bt_ov,
       const int* __restrict__ bt_ix,
       float* __restrict__ lossc,
       float* __restrict__ ce_neg,
       int* __restrict__ num_pos,
       float* __restrict__ accum) {
    __shared__ float srow[RPB * C_];          // 41472 B
    const int row0 = blockIdx.x * RPB;
    const int tid = threadIdx.x;

    // ---- stage: 2592 float4 = RPB*C_/4, issue all loads first ----
    {
        const float4* src = (const float4*)(conf_data + (size_t)row0 * C_);
        float4* dst = (float4*)srow;
        const int n4 = RPB * C_ / 4;          // 2592
        float4 tmp[21];
        #pragma unroll
        for (int k = 0; k < 21; ++k) {
            int i = tid + k * RPB;
            if (i < n4) tmp[k] = src[i];
        }
        #pragma unroll
        for (int k = 0; k < 21; ++k) {
            int i = tid + k * RPB;
            if (i < n4) dst[i] = tmp[k];
        }
    }
    __syncthreads();

    const int bp = row0 + tid;
    const int b = bp / P_;
    const int p = bp - b * P_;
    const float* row = srow + tid * C_;

    // ---- logsumexp over 81, 4-way ILP ----
    float m0 = -INFINITY, m1 = -INFINITY, m2 = -INFINITY, m3 = -INFINITY;
    #pragma unroll
    for (int j = 0; j < 80; j += 4) {
        m0 = fmaxf(m0, row[j]);     m1 = fmaxf(m1, row[j + 1]);
        m2 = fmaxf(m2, row[j + 2]); m3 = fmaxf(m3, row[j + 3]);
    }
    float m = fmaxf(fmaxf(fmaxf(m0, m1), fmaxf(m2, m3)), row[80]);
    float s0 = 0.f, s1 = 0.f, s2 = 0.f, s3 = 0.f;
    #pragma unroll
    for (int j = 0; j < 80; j += 4) {
        s0 += __expf(row[j] - m);     s1 += __expf(row[j + 1] - m);
        s2 += __expf(row[j + 2] - m); s3 += __expf(row[j + 3] - m);
    }
    float logZ = m + __logf((s0 + s1) + (s2 + s3) + __expf(row[80] - m));

    // ---- conf_t classification ----
    float ov = bt_ov[bp];
    int ti = bt_ix[bp];
    int conf_t = gt_labels[b * O_ + ti] + 1;
    if (ov < POS_TH) conf_t = -1;
    if (ov < NEG_TH) conf_t = 0;
    bool pos = conf_t > 0;

    float conf0 = row[0];
    float lc = (pos || conf_t < 0) ? 0.0f : (logZ - conf0);
    int cls = pos ? conf_t : 0;
    float ce = logZ - row[cls];

    lossc[bp] = lc;
    ce_neg[bp] = (conf_t == 0) ? ce : 0.0f;

    __shared__ float s_lB, s_ceP;
    __shared__ int s_np;
    if (tid == 0) { s_lB = 0.0f; s_ceP = 0.0f; s_np = 0; }
    __syncthreads();

    if (pos) {
        float4 t = ((const float4*)gt_boxes)[b * O_ + ti];   // matched gt (point form)
        float4 pr = ((const float4*)priors)[p];              // prior (center form)
        float mcx = (t.x + t.z) * 0.5f;
        float mcy = (t.y + t.w) * 0.5f;
        float gx = (mcx - pr.x) / (0.1f * pr.z);
        float gy = (mcy - pr.y) / (0.1f * pr.w);
        float gw = logf((t.z - t.x) / pr.z) / 0.2f;
        float gh = logf((t.w - t.y) / pr.w) / 0.2f;
        float4 ld = ((const float4*)loc_data)[bp];
        float s = sl1(ld.x - gx) + sl1(ld.y - gy) + sl1(ld.z - gw) + sl1(ld.w - gh);
        atomicAdd(&s_lB, s);
        atomicAdd(&s_ceP, ce);
        atomicAdd(&s_np, 1);
    }
    __syncthreads();
    if (tid == 0 && s_np > 0) {
        atomicAdd(&accum[0], s_lB);
        atomicAdd(&accum[1], s_ceP);
        atomicAdd(&num_pos[b], s_np);
    }
}

// One block per batch: exact top-k via 64-bit radix select.
// key = float_bits(loss_c) << 32 | ~index  == stable argsort(-loss_c) order.
__global__ void k_select(const float* __restrict__ lossc,
                         const float* __restrict__ ce_neg,
                         const int* __restrict__ num_pos,
                         float* __restrict__ ce_sum) {
    int b = blockIdx.x;
    const float* lc = lossc + (size_t)b * P_;
    const float* cn = ce_neg + (size_t)b * P_;
    int k = 3 * num_pos[b];
    if (k > P_ - 1) k = P_ - 1;

    __shared__ int hist[256];
    __shared__ unsigned long long s_prefix;
    __shared__ int s_k;
    if (threadIdx.x == 0) { s_prefix = 0ULL; s_k = k; }
    __syncthreads();

    if (k <= 0) {
        if (threadIdx.x == 0) ce_sum[b] = 0.0f;
        return;
    }

    for (int d = 7; d >= 0; --d) {
        for (int i = threadIdx.x; i < 256; i += blockDim.x) hist[i] = 0;
        __syncthreads();
        unsigned long long pref = s_prefix;
        unsigned long long pmask = (d == 7) ? 0ULL : ((~0ULL) << ((d + 1) * 8));
        for (int i = threadIdx.x; i < P_; i += blockDim.x) {
            unsigned int fb = __float_as_uint(lc[i]);
            unsigned long long key =
                ((unsigned long long)fb << 32) | (unsigned int)(0xFFFFFFFFu - (unsigned int)i);
            if ((key & pmask) == pref)
                atomicAdd(&hist[(int)((key >> (d * 8)) & 255)], 1);
        }
        __syncthreads();
        if (threadIdx.x == 0) {
            int kk = s_k, cum = 0, bin = 255;
            for (; bin >= 1; --bin) {
                if (cum + hist[bin] >= kk) break;
                cum += hist[bin];
            }
            s_prefix = pref | ((unsigned long long)bin << (d * 8));
            s_k = kk - cum;
        }
        __syncthreads();
    }

    unsigned long long T = s_prefix;
    float sum = 0.0f;
    for (int i = threadIdx.x; i < P_; i += blockDim.x) {
        unsigned int fb = __float_as_uint(lc[i]);
        unsigned long long key =
            ((unsigned long long)fb << 32) | (unsigned int)(0xFFFFFFFFu - (unsigned int)i);
        if (key >= T) sum += cn[i];
    }
    __shared__ float red[1024];
    red[threadIdx.x] = sum;
    __syncthreads();
    for (int s = (int)blockDim.x / 2; s > 0; s >>= 1) {
        if (threadIdx.x < s) red[threadIdx.x] += red[threadIdx.x + s];
        __syncthreads();
    }
    if (threadIdx.x == 0) ce_sum[b] = red[0];
}

__global__ void k_final(const int* __restrict__ num_pos,
                        const float* __restrict__ ce_sum,
                        const float* __restrict__ accum,
                        float* __restrict__ out) {
    if (threadIdx.x != 0) return;
    int tp = 0; float ns = 0.0f;
    for (int b = 0; b < B_; ++b) { tp += num_pos[b]; ns += ce_sum[b]; }
    float inv = 1.0f / (float)tp;
    out[0] = accum[0] * 1.5f * inv;          // BBOX_ALPHA
    out[1] = (accum[1] + ns) * 1.0f * inv;   // CONF_ALPHA
}

extern "C" void kernel_launch(void* const* d_in, const int* in_sizes, int n_in,
                              void* d_out, int out_size, void* d_ws, size_t ws_size,
                              hipStream_t stream) {
    const float* loc    = (const float*)d_in[0];
    const float* conf   = (const float*)d_in[1];
    const float* priors = (const float*)d_in[2];
    const float* gtb    = (const float*)d_in[3];
    const int*   gtl    = (const int*)d_in[4];
    float* out = (float*)d_out;

    const size_t BP = (size_t)B_ * P_;
    float* bt_ov   = (float*)d_ws;
    int*   bt_ix   = (int*)d_ws + BP;
    float* lossc   = (float*)d_ws + 2 * BP;
    float* ce_neg  = (float*)d_ws + 3 * BP;
    int*   best_pr = (int*)d_ws + 4 * BP;
    int*   num_pos = (int*)d_ws + 4 * BP + B_ * O_;
    float* ce_sum  = (float*)d_ws + 4 * BP + B_ * O_ + B_;
    float* accum   = (float*)d_ws + 4 * BP + B_ * O_ + 2 * B_;

    hipLaunchKernelGGL(k_init, dim3(1), dim3(64), 0, stream, num_pos, accum);
    hipLaunchKernelGGL(k_best_prior, dim3(B_ * O_), dim3(256), 0, stream,
                       priors, gtb, best_pr);
    hipLaunchKernelGGL(k_best_truth, dim3((P_ + 255) / 256, B_), dim3(256), 0, stream,
                       priors, gtb, bt_ov, bt_ix);
    hipLaunchKernelGGL(k_force, dim3(1), dim3(64), 0, stream, best_pr, bt_ov, bt_ix);
    hipLaunchKernelGGL(k_main, dim3((int)(BP / RPB)), dim3(RPB), 0, stream,
                       loc, conf, priors, gtb, gtl, bt_ov, bt_ix,
                       lossc, ce_neg, num_pos, accum);
    hipLaunchKernelGGL(k_select, dim3(B_), dim3(1024), 0, stream,
                       lossc, ce_neg, num_pos, ce_sum);
    hipLaunchKernelGGL(k_final, dim3(1), dim3(64), 0, stream,
                       num_pos, ce_sum, accum, out);
}